// Round 21
// baseline (1752.699 us; speedup 1.0000x reference)
//
#include <hip/hip_runtime.h>
#include <hip/hip_bf16.h>

#define B_N 4096
#define L_N 32
#define C_N 28
#define H_N 512
#define T_N 32
#define G_N 2048     // 4*H
#define KPA 1088     // A row: [h_hi 0..512 | ctx_hi 512..544 | h_lo 544..1056 | ctx_lo 1056..1088]
#define KW2 576      // W2 row: [whh_lo 512 | wih_lo 28 | 36 zeros]

// R21: swizzled BK=64 MFMA GEMM + epilogue attention dots (atomics) + tiny ctx kernel
// + coalesced prep_x. 3-term hi/lo scheme unchanged (R20: absmax 0.0078).

typedef __attribute__((ext_vector_type(4))) float f32x4;
typedef __attribute__((ext_vector_type(8))) short s16x8;

static constexpr size_t OFF_W1 = 0;                                    // bf16 [2048][1088]
static constexpr size_t OFF_W2 = OFF_W1 + (size_t)G_N * KPA * 2;       // bf16 [2048][576]
static constexpr size_t AB_ONE = (size_t)B_N * KPA * 2;
static constexpr size_t OFF_AB = OFF_W2 + (size_t)G_N * KW2 * 2;       // bf16 [2][4096][1088]
static constexpr size_t OFF_X  = OFF_AB + 2 * AB_ONE;                  // f32 [4096][32][28]
static constexpr size_t OFF_UA = OFF_X + (size_t)B_N * L_N * C_N * 4;  // f32 [4096][32]
static constexpr size_t OFF_BS = OFF_UA + (size_t)B_N * L_N * 4;       // f32 [2048]
static constexpr size_t OFF_AC = OFF_BS + 8192;                        // f32 accW[4096], accO[4096]
static constexpr size_t OFF_CS = OFF_AC + 32768;                       // f32 [4096][512]
static constexpr size_t WS_NEED = OFF_CS + (size_t)B_N * H_N * 4;      // ~48.3 MB

__device__ __forceinline__ float bf2f(short s) {
    union { unsigned int u; float f; } v;
    v.u = ((unsigned int)(unsigned short)s) << 16;
    return v.f;
}
__device__ __forceinline__ float sigmoidf_(float x) { return 1.f / (1.f + __expf(-x)); }
__device__ __forceinline__ float tanhf_(float x) {
    float ax = fabsf(x), e = __expf(-2.f * ax);
    float t = (1.f - e) / (1.f + e);
    return x < 0.f ? -t : t;
}
__device__ __forceinline__ void load16_lds(const void* g, void* l) {
    __builtin_amdgcn_global_load_lds((__attribute__((address_space(1))) void*)g,
                                     (__attribute__((address_space(3))) void*)l,
                                     16, 0, 0);
}

__global__ __launch_bounds__(256) void fill_out(float* out, float v) {
    int i = blockIdx.x * 256 + threadIdx.x;
    if (i < B_N * 32) out[i] = v;
}

// ---------------- prep_x: conv1 residual block, x (coalesced), u_a ----------------
__global__ void prep_x(const float* __restrict__ input, const float* __restrict__ mask,
                       const float* __restrict__ w1, const float* __restrict__ b1,
                       const float* __restrict__ cw, const float* __restrict__ cb,
                       float* __restrict__ x, float* __restrict__ ua)
{
    __shared__ float sw1[C_N * C_N * 3];
    __shared__ float sb1[C_N], scw[C_N];
    __shared__ float sxb[8 * L_N * C_N];          // 8 rows x 896 f32 = 28 KB
    for (int i = threadIdx.x; i < C_N * C_N * 3; i += blockDim.x) sw1[i] = w1[i];
    if (threadIdx.x < C_N) { sb1[threadIdx.x] = b1[threadIdx.x]; scw[threadIdx.x] = cw[threadIdx.x]; }
    __syncthreads();
    int idx = blockIdx.x * blockDim.x + threadIdx.x;   // [0, B*L)
    int b = idx >> 5, l = idx & 31;
    int wv = threadIdx.x >> 5;                    // local row 0..7
    float m = mask[idx];
    const float* inb = input + (size_t)b * (L_N * C_N);
    float xin[3][C_N];
    #pragma unroll
    for (int k = 0; k < 3; ++k) {
        int ll = l + k - 1;
        if (ll >= 0 && ll < L_N) {
            for (int c = 0; c < C_N; ++c) xin[k][c] = inb[ll * C_N + c];
        } else {
            for (int c = 0; c < C_N; ++c) xin[k][c] = 0.f;
        }
    }
    float uacc = 0.f;
    for (int o = 0; o < C_N; ++o) {
        float y = sb1[o];
        const float* wo = sw1 + o * (C_N * 3);
        for (int i = 0; i < C_N; ++i) {
            y += wo[i * 3 + 0] * xin[0][i];
            y += wo[i * 3 + 1] * xin[1][i];
            y += wo[i * 3 + 2] * xin[2][i];
        }
        y *= m;
        float e = (y > 0.f) ? y : (__expf(y) - 1.f);   // ELU
        float xv = e + xin[1][o];                      // residual
        sxb[wv * (L_N * C_N) + l * C_N + o] = xv;
        uacc += xv * scw[o];
    }
    ua[idx] = (uacc + cb[0]) * m;
    __syncthreads();
    // coalesced copy: 8*896 = 7168 floats
    float* xdst = x + (size_t)blockIdx.x * (8 * L_N * C_N);
    for (int i = threadIdx.x; i < 8 * L_N * C_N; i += 256) xdst[i] = sxb[i];
}

// ---------------- prep_w: hi/lo split, perm p = unit*4+gate ----------------
__global__ void prep_w(const float* __restrict__ w_ih, const float* __restrict__ w_hh,
                       const float* __restrict__ b_ih, const float* __restrict__ b_hh,
                       __hip_bfloat16* __restrict__ W1, __hip_bfloat16* __restrict__ W2,
                       float* __restrict__ bsum)
{
    int p = blockIdx.x;            // [0,2048)
    int j = p >> 2, g = p & 3;
    int srow = g * H_N + j;
    for (int k = threadIdx.x; k < KW2; k += blockDim.x) {
        float v = 0.f;
        if (k < 512) v = w_hh[(size_t)srow * H_N + k];
        else if (k < 540) v = w_ih[srow * C_N + (k - 512)];
        __hip_bfloat16 hi = __float2bfloat16(v);
        __hip_bfloat16 lo = __float2bfloat16(v - __bfloat162float(hi));
        if (k < 544) {
            W1[(size_t)p * KPA + k]       = hi;
            W1[(size_t)p * KPA + 544 + k] = hi;
        }
        W2[(size_t)p * KW2 + k] = lo;
    }
    if (threadIdx.x == 0) bsum[p] = b_ih[srow] + b_hh[srow];
}

// ---------------- prep_zero: A bufs, cstate, accums ----------------
__global__ void prep_zero(unsigned int* __restrict__ a32, float* __restrict__ cst,
                          float* __restrict__ acc)
{
    int idx = blockIdx.x * blockDim.x + threadIdx.x;
    if (idx < B_N * KPA) a32[idx] = 0u;            // both A buffers: 2*B*KPA*2B = B*KPA words
    if (idx < B_N * H_N) cst[idx] = 0.f;
    if (idx < 2 * B_N) acc[idx] = 0.f;
}

// ---------------- params ----------------
struct RParams {
    const float* mask;
    const float* bias_mat;
    const float* fc1_w;
    const float* fc1_b;
    const float* conv2_w;
    const float* conv2_b;
    const __hip_bfloat16* W1;
    const __hip_bfloat16* W2;
    const __hip_bfloat16* Ain;
    __hip_bfloat16* Aout;
    const float* x;
    const float* ua;
    const float* bsum;
    float* accW;
    float* accO;
    float* cstate;
    float* out;                  // f32 output
};

// ---------------- ctx_step: softmax+context from accumulated dots; out write ----------------
__global__ __launch_bounds__(256) void ctx_step(RParams P, int t)
{
    const int lane = threadIdx.x & 63;
    const int wave = threadIdx.x >> 6;
    const int row  = blockIdx.x * 4 + wave;     // [0, 4096)

    float aW = P.accW[row];
    float aO = P.accO[row];
    if (t > 0 && lane == 0)
        P.out[row * T_N + (t - 1)] = (aO + P.conv2_b[0]) * P.mask[row * L_N + (t - 1)];

    if (t < T_N) {
        if (lane == 0) { P.accW[row] = 0.f; P.accO[row] = 0.f; }
        float w_a = aW + P.fc1_b[0];
        int l32 = lane & 31;
        float e = P.ua[row * L_N + l32] + w_a;
        e = (e > 0.f) ? e : 0.01f * e;              // leaky_relu
        e += P.bias_mat[row * L_N + l32];
        float mx = e;
        #pragma unroll
        for (int off = 16; off > 0; off >>= 1) mx = fmaxf(mx, __shfl_xor(mx, off, 32));
        float pexp = __expf(e - mx);
        float ssum = pexp;
        #pragma unroll
        for (int off = 16; off > 0; off >>= 1) ssum += __shfl_xor(ssum, off, 32);
        float p = pexp / ssum;
        int cc = (lane < C_N) ? lane : 0;
        const float* xrow = P.x + (size_t)row * (L_N * C_N) + cc;
        float ctx = 0.f;
        #pragma unroll
        for (int l = 0; l < L_N; ++l) {
            float al = __shfl(p, l);                // lanes 0..31 hold attn
            ctx += al * xrow[l * C_N];
        }
        if (lane < C_N) {
            __hip_bfloat16 hi = __float2bfloat16(ctx);
            __hip_bfloat16 lo = __float2bfloat16(ctx - __bfloat162float(hi));
            P.Aout[(size_t)row * KPA + 512 + lane]  = hi;
            P.Aout[(size_t)row * KPA + 1056 + lane] = lo;
        }
    }
}

// ---------------- gemm_cell_step: 26 chunks BK=64 swizzled + cell + partial dots ----------------
__global__ __launch_bounds__(256) void gemm_cell_step(RParams P)
{
    __shared__ __align__(16) char smem[65536];   // A dbuf 2x16K @0, W dbuf 2x16K @32768; gates reuse @0

    const int tid  = threadIdx.x;
    const int lane = tid & 63;
    const int wave = tid >> 6;         // 4 waves
    const int bid  = blockIdx.x;       // 512 WGs
    const int m    = bid >> 4;
    const int n    = bid & 15;
    const int wm   = wave >> 1, wn = wave & 1;

    const __hip_bfloat16* Ag  = P.Ain + (size_t)(m * 128) * KPA;
    const __hip_bfloat16* W1g = P.W1  + (size_t)(n * 128) * KPA;
    const __hip_bfloat16* W2g = P.W2  + (size_t)(n * 128) * KW2;

    // swizzled staging map: slot s=(wave*4+j)*64+lane -> row=s>>3, egrp=(s&7)^(row&7)
    int srow[4], seg[4];
    #pragma unroll
    for (int j = 0; j < 4; ++j) {
        int s = (wave * 4 + j) * 64 + lane;
        srow[j] = s >> 3;
        seg[j] = (s & 7) ^ ((s >> 3) & 7);
    }

    f32x4 acc[4][4];
    #pragma unroll
    for (int i = 0; i < 4; ++i)
        #pragma unroll
        for (int j2 = 0; j2 < 4; ++j2)
            acc[i][j2] = (f32x4){0.f, 0.f, 0.f, 0.f};

    auto stage = [&](int kc, int buf) {
        #pragma unroll
        for (int j = 0; j < 4; ++j) {
            char* adst = smem + buf * 16384 + ((wave * 4 + j) * 64 + lane) * 16;
            char* wdst = smem + 32768 + buf * 16384 + ((wave * 4 + j) * 64 + lane) * 16;
            const __hip_bfloat16 *asrc, *wsrc;
            if (kc < 17) {
                asrc = Ag  + (size_t)srow[j] * KPA + kc * 64 + seg[j] * 8;
                wsrc = W1g + (size_t)srow[j] * KPA + kc * 64 + seg[j] * 8;
            } else {
                asrc = Ag  + (size_t)srow[j] * KPA + (kc - 17) * 64 + seg[j] * 8;
                wsrc = W2g + (size_t)srow[j] * KW2 + (kc - 17) * 64 + seg[j] * 8;
            }
            load16_lds(asrc, adst);
            load16_lds(wsrc, wdst);
        }
    };

    stage(0, 0);
    const int rA = lane & 15;
    const int gq = lane >> 4;
    const int r7 = lane & 7;
    for (int kc = 0; kc < 26; ++kc) {
        __syncthreads();
        if (kc + 1 < 26) stage(kc + 1, (kc + 1) & 1);
        const char* Ab = smem + (kc & 1) * 16384;
        const char* Bb = smem + 32768 + (kc & 1) * 16384;
        #pragma unroll
        for (int ks = 0; ks < 2; ++ks) {
            const int sw = ((ks * 4 + gq) ^ r7) * 16;      // swizzled 16B group offset
            s16x8 afr[4], bfr[4];
            #pragma unroll
            for (int i = 0; i < 4; ++i) {
                int r = wm * 64 + i * 16 + rA;
                int pr = wn * 64 + i * 16 + rA;
                afr[i] = *(const s16x8*)(Ab + r * 128 + sw);
                bfr[i] = *(const s16x8*)(Bb + pr * 128 + sw);
            }
            #pragma unroll
            for (int i = 0; i < 4; ++i)
                #pragma unroll
                for (int j2 = 0; j2 < 4; ++j2)
                    acc[i][j2] = __builtin_amdgcn_mfma_f32_16x16x32_bf16(afr[i], bfr[j2], acc[i][j2], 0, 0, 0);
        }
    }

    // ---- epilogue: gates via LDS, cell update, h hi/lo write, partial attention dots ----
    __syncthreads();
    float* gates = (float*)smem;     // 128 x 64 f32 = 32 KB
    #pragma unroll
    for (int hh = 0; hh < 2; ++hh) {
        if (wn == hh) {
            #pragma unroll
            for (int i = 0; i < 4; ++i)
                #pragma unroll
                for (int j2 = 0; j2 < 4; ++j2)
                    #pragma unroll
                    for (int r = 0; r < 4; ++r) {
                        int rowl = wm * 64 + i * 16 + (lane >> 4) * 4 + r;
                        int coll = j2 * 16 + (lane & 15);
                        gates[rowl * 64 + coll] = acc[i][j2][r];
                    }
        }
        __syncthreads();
        {
            int u = tid & 15, rr = tid >> 4;
            int unit = n * 32 + hh * 16 + u;
            f32x4 bsv = *(const f32x4*)(P.bsum + unit * 4);
            float f1v = P.fc1_w[unit];
            float c2v = P.conv2_w[unit];
            #pragma unroll
            for (int it = 0; it < 8; ++it) {
                int rowl = it * 16 + rr;
                int grow = m * 128 + rowl;
                f32x4 gv = *(const f32x4*)(gates + rowl * 64 + u * 4);
                float pi = gv.x + bsv.x;
                float pf = gv.y + bsv.y;
                float pg = gv.z + bsv.z;
                float po = gv.w + bsv.w;
                float* cp = P.cstate + (size_t)grow * H_N + unit;
                float c = sigmoidf_(pf) * (*cp) + sigmoidf_(pi) * tanhf_(pg);
                *cp = c;
                float h = sigmoidf_(po) * tanhf_(c);
                __hip_bfloat16 hi = __float2bfloat16(h);
                __hip_bfloat16 lo = __float2bfloat16(h - __bfloat162float(hi));
                P.Aout[(size_t)grow * KPA + unit]       = hi;
                P.Aout[(size_t)grow * KPA + 544 + unit] = lo;
                // partial attention dots over this 16-unit group
                float wd = f1v * h, od = c2v * h;
                #pragma unroll
                for (int off = 8; off > 0; off >>= 1) {
                    wd += __shfl_xor(wd, off);
                    od += __shfl_xor(od, off);
                }
                if (u == 0) {
                    atomicAdd(P.accW + grow, wd);
                    atomicAdd(P.accO + grow, od);
                }
            }
        }
        __syncthreads();
    }
}

extern "C" void kernel_launch(void* const* d_in, const int* in_sizes, int n_in,
                              void* d_out, int out_size, void* d_ws, size_t ws_size,
                              hipStream_t stream)
{
    float* out = (float*)d_out;
    if (ws_size < WS_NEED) { fill_out<<<512, 256, 0, stream>>>(out, 4000.f); return; }

    const float* input = (const float*)d_in[0];
    const float* mask  = (const float*)d_in[1];
    const float* biasm = (const float*)d_in[2];
    const float* w1    = (const float*)d_in[3];
    const float* b1    = (const float*)d_in[4];
    const float* cw    = (const float*)d_in[5];
    const float* cb    = (const float*)d_in[6];
    const float* w_ih  = (const float*)d_in[7];
    const float* w_hh  = (const float*)d_in[8];
    const float* b_ih  = (const float*)d_in[9];
    const float* b_hh  = (const float*)d_in[10];
    const float* fc1w  = (const float*)d_in[11];
    const float* fc1b  = (const float*)d_in[12];
    const float* c2w   = (const float*)d_in[13];
    const float* c2b   = (const float*)d_in[14];

    char* ws = (char*)d_ws;
    __hip_bfloat16* W1    = (__hip_bfloat16*)(ws + OFF_W1);
    __hip_bfloat16* W2    = (__hip_bfloat16*)(ws + OFF_W2);
    __hip_bfloat16* Abuf0 = (__hip_bfloat16*)(ws + OFF_AB);
    __hip_bfloat16* Abuf1 = (__hip_bfloat16*)(ws + OFF_AB + AB_ONE);
    float* x    = (float*)(ws + OFF_X);
    float* ua   = (float*)(ws + OFF_UA);
    float* bsum = (float*)(ws + OFF_BS);
    float* accW = (float*)(ws + OFF_AC);
    float* accO = (float*)(ws + OFF_AC + 16384);
    float* cst  = (float*)(ws + OFF_CS);

    prep_x<<<(B_N * L_N) / 256, 256, 0, stream>>>(input, mask, w1, b1, cw, cb, x, ua);
    prep_w<<<G_N, 256, 0, stream>>>(w_ih, w_hh, b_ih, b_hh, W1, W2, bsum);
    prep_zero<<<(B_N * KPA + 255) / 256, 256, 0, stream>>>((unsigned int*)Abuf0, cst, accW);

    RParams P;
    P.mask = mask; P.bias_mat = biasm; P.fc1_w = fc1w; P.fc1_b = fc1b;
    P.conv2_w = c2w; P.conv2_b = c2b; P.W1 = W1; P.W2 = W2;
    P.x = x; P.ua = ua; P.bsum = bsum; P.accW = accW; P.accO = accO;
    P.cstate = cst; P.out = out;

    __hip_bfloat16* bufs[2] = { Abuf0, Abuf1 };
    for (int t = 0; t < T_N; ++t) {
        P.Ain  = bufs[t & 1];
        P.Aout = bufs[t & 1];                       // ctx written into current buffer
        ctx_step<<<B_N / 4, 256, 0, stream>>>(P, t);
        P.Ain  = bufs[t & 1];
        P.Aout = bufs[(t + 1) & 1];                 // h_{t+1} into other buffer
        gemm_cell_step<<<512, 256, 0, stream>>>(P);
    }
    P.Ain = bufs[T_N & 1];
    P.Aout = bufs[T_N & 1];
    ctx_step<<<B_N / 4, 256, 0, stream>>>(P, T_N);  // out[:, T-1]
}